// Round 4
// baseline (1010.899 us; speedup 1.0000x reference)
//
#include <hip/hip_runtime.h>
#include <hip/hip_bf16.h>

// BFConv2d on MI355X: BFP(8,16)-quantize x and w to bf16 (exact: q in
// [-127,127] * 2^(e-7) has <=8 significant bits), then implicit-GEMM 3x3
// conv with mfma_f32_16x16x32_bf16, fp32 accumulation.
// x (64,128,56,56) f32 NCHW; w (128,128,3,3) f32 OIHW; out (64,128,56,56) f32.
//
// r4: conv Xs is SINGLE-buffered (27.8KB) with split staging (reg-load at
// rs0, ds_write between two barriers at rs8) -> 4 blocks/CU, whole 896-block
// grid co-resident (no dispatch tail). launch_bounds(256,4) pins VGPR<=128.
// s_setprio around MFMA cluster (independent blocks per CU). Weight A-frags
// stay global/L2 with 1-step register prefetch; XCD-swizzled blockIdx.

using short8 = __attribute__((ext_vector_type(8))) short;
using f32x4  = __attribute__((ext_vector_type(4))) float;
using int4v  = __attribute__((ext_vector_type(4))) int;

#define XS_STRIDE_S 40                      // shorts per Xs row (80B: 16B-aligned)
#define XS_ENT      348                     // 6 rows x 58 cols
#define XS_BUF_S    (XS_ENT * XS_STRIDE_S)  // 13920 shorts = 27,840B

__device__ __forceinline__ unsigned short f2bf(float f) {
    union { float f; unsigned u; } v; v.f = f;
    return (unsigned short)(v.u >> 16);     // quantized values exact in bf16
}

__device__ __forceinline__ void quant16(const float* v, float* o) {
    float m = 0.f;
    #pragma unroll
    for (int i = 0; i < 16; ++i) m = fmaxf(m, fabsf(v[i]));
    if (m > 0.f) {
        float e     = floorf(log2f(m));     // matches jnp.floor(jnp.log2(m))
        float scale = exp2f(e - 7.0f);
        float inv   = exp2f(7.0f - e);
        #pragma unroll
        for (int i = 0; i < 16; ++i) {
            float q = rintf(v[i] * inv);    // round half-to-even == jnp.round
            q = fminf(fmaxf(q, -127.f), 127.f);
            o[i] = q * scale;
        }
    } else {
        #pragma unroll
        for (int i = 0; i < 16; ++i) o[i] = 0.f;
    }
}

// Fused quantization. Blocks 0..3135: x NCHW f32 -> xq NHWC bf16 via LDS
// transpose (tile = 128c x 64px). Blocks 3136..3171: w OIHW f32 ->
// wq [cblk][rs][k][c32] bf16. Groups of 16 never straddle tiles.
__global__ __launch_bounds__(256) void quant_kernel(const float* __restrict__ x,
                                                    const float* __restrict__ w,
                                                    unsigned short* __restrict__ xq,
                                                    unsigned short* __restrict__ wq) {
    __shared__ float T[128 * 68];           // 34,816B; row stride 68 (272B)
    const int bid = blockIdx.x;
    const int t   = threadIdx.x;

    if (bid < 3136) {
        const int n  = bid / 49;
        const int p0 = (bid % 49) * 64;
        const float* src = x + (size_t)n * 128 * 3136 + p0;

        // Phase 1: coalesced NCHW read (4x256B full-line segments per inst).
        #pragma unroll
        for (int i = 0; i < 8; ++i) {
            const int c  = (t >> 4) + i * 16;
            const int ch = t & 15;
            *reinterpret_cast<float4*>(&T[c * 68 + ch * 4]) =
                *reinterpret_cast<const float4*>(src + (size_t)c * 3136 + ch * 4);
        }
        __syncthreads();

        // Phase 2: thread = one (c, 16-px group); NHWC writes coalesce to
        // 128B lines across the 64 c-lanes.
        const int c = t & 127;
        #pragma unroll
        for (int i = 0; i < 2; ++i) {
            const int grp = (t >> 7) + 2 * i;
            float v[16];
            #pragma unroll
            for (int j2 = 0; j2 < 4; ++j2) {
                float4 f = *reinterpret_cast<const float4*>(&T[c * 68 + grp * 16 + j2 * 4]);
                v[j2*4+0] = f.x; v[j2*4+1] = f.y; v[j2*4+2] = f.z; v[j2*4+3] = f.w;
            }
            float o[16];
            quant16(v, o);
            unsigned short* dst = xq + ((size_t)(n * 3136 + p0 + grp * 16)) * 128 + c;
            #pragma unroll
            for (int j = 0; j < 16; ++j) dst[(size_t)j * 128] = f2bf(o[j]);
        }
    } else {
        const int G    = (bid - 3136) * 256 + t;   // 0..9215
        const int k    = G / 72;
        const int base = (G % 72) * 16;            // flat idx2 = c*9 + r*3 + s
        const float* src = w + (size_t)k * 1152 + base;
        float v[16];
        #pragma unroll
        for (int i = 0; i < 4; ++i) {
            float4 f = *reinterpret_cast<const float4*>(src + i * 4);
            v[i*4+0] = f.x; v[i*4+1] = f.y; v[i*4+2] = f.z; v[i*4+3] = f.w;
        }
        float o[16];
        quant16(v, o);
        #pragma unroll
        for (int j = 0; j < 16; ++j) {
            int idx2 = base + j;
            int c  = idx2 / 9;
            int rs = idx2 % 9;
            wq[(((size_t)(c >> 5) * 9 + rs) * 128 + k) * 32 + (c & 31)] = f2bf(o[j]);
        }
    }
}

// Implicit-GEMM conv. Per WG: n fixed, 4 output rows (224 px = 4x56), all 128 k.
// Waves 2x2: wave tile = 112 px x 64 k = 7 M-frags x 4 N-frags (16x16x32 bf16).
// A-op = weights from L2-resident GLOBAL (1-step reg prefetch),
// B-op = Xs pixels from LDS (single buffer, split staging), K-dim = c.
__global__ __launch_bounds__(256, 4) void conv_kernel(const unsigned short* __restrict__ xq,
                                                      const unsigned short* __restrict__ wq,
                                                      float* __restrict__ out) {
    __shared__ __align__(16) unsigned short Xs[XS_BUF_S];   // 27,840B -> 4 blocks/CU

    const int b0   = blockIdx.x;          // 896 = 64 n * 14 h-tiles
    const int bid  = (b0 & 7) * 112 + (b0 >> 3);   // XCD swizzle (bijective: 896%8==0)
    const int n    = bid / 14;
    const int h0   = (bid % 14) * 4;
    const int t    = threadIdx.x;
    const int lane = t & 63;
    const int wave = t >> 6;
    const int mw   = wave >> 1;           // pixel half
    const int nw   = wave & 1;            // k half

    // ---- staging descriptors: 6 x 16B chunks per thread, fixed across cblk ----
    const unsigned short* sbase[6];
    int  soff[6];
    bool svalid[6], sact[6];
    #pragma unroll
    for (int it = 0; it < 6; ++it) {
        int i   = t + it * 256;
        bool act = i < 1392;              // 348 entries * 4 chunks
        int e   = i >> 2, cc = i & 3;
        int row = e / 58, pw = e % 58;
        int h   = h0 - 1 + row, w_ = pw - 1;
        bool inb = act && (unsigned)h < 56u && (unsigned)w_ < 56u;
        int gidx = inb ? (n * 3136 + h * 56 + w_) : 0;
        sbase[it]  = xq + (size_t)gidx * 128 + cc * 8;
        soff[it]   = e * XS_STRIDE_S + cc * 8;
        svalid[it] = inb;
        sact[it]   = act;
    }
    int4v sreg[6];

#define STAGE_LOAD(CB) do {                                                    \
    _Pragma("unroll")                                                          \
    for (int it = 0; it < 6; ++it)                                             \
        sreg[it] = svalid[it]                                                  \
            ? *reinterpret_cast<const int4v*>(sbase[it] + (CB) * 32)           \
            : int4v{0, 0, 0, 0};                                               \
} while (0)

#define STAGE_WRITE() do {                                                     \
    _Pragma("unroll")                                                          \
    for (int it = 0; it < 6; ++it)                                             \
        if (sact[it])                                                          \
            *reinterpret_cast<int4v*>(Xs + soff[it]) = sreg[it];               \
} while (0)

    // ---- per-lane fragment offsets ----
    int boff[7];                          // B-frag (pixels) LDS short-offsets
    #pragma unroll
    for (int fi = 0; fi < 7; ++fi) {
        int m  = mw * 112 + fi * 16 + (lane & 15);
        int dh = m / 56, w_ = m % 56;
        boff[fi] = (dh * 58 + w_) * XS_STRIDE_S + ((lane >> 4) * 8);
    }
    // A-frag element: (step*128 + nw*64 + ni*16 + (lane&15))*32 + (lane>>4)*8
    const unsigned short* wk = wq + (size_t)(nw * 64 + (lane & 15)) * 32 + ((lane >> 4) * 8);

#define LOADA(DST, STEP) do {                                                  \
    _Pragma("unroll")                                                          \
    for (int ni = 0; ni < 4; ++ni)                                             \
        DST[ni] = *reinterpret_cast<const short8*>(                            \
            wk + (size_t)(STEP) * 4096 + ni * 512);                            \
} while (0)

    f32x4 acc[7][4];
    #pragma unroll
    for (int fi = 0; fi < 7; ++fi)
        #pragma unroll
        for (int ni = 0; ni < 4; ++ni)
            acc[fi][ni] = f32x4{0.f, 0.f, 0.f, 0.f};

    short8 a_cur[4], a_nxt[4];

    // ---- prologue: stage cblk 0; preload step-0 weights ----
    STAGE_LOAD(0);
    LOADA(a_cur, 0);
    STAGE_WRITE();
    __syncthreads();

    #pragma unroll
    for (int step = 0; step < 36; ++step) {
        const int cblk = step / 9;
        const int rs   = step % 9;

        if (step < 35) LOADA(a_nxt, step + 1);          // prefetch next weights
        if (rs == 0 && cblk < 3) STAGE_LOAD(cblk + 1);  // issue next-cblk x loads

        const int rsS = ((rs / 3) * 58 + (rs % 3)) * XS_STRIDE_S;
        short8 b[7];
        #pragma unroll
        for (int fi = 0; fi < 7; ++fi)
            b[fi] = *reinterpret_cast<const short8*>(Xs + boff[fi] + rsS);

        __builtin_amdgcn_s_setprio(1);
        #pragma unroll
        for (int fi = 0; fi < 7; ++fi)
            #pragma unroll
            for (int ni = 0; ni < 4; ++ni)
                acc[fi][ni] = __builtin_amdgcn_mfma_f32_16x16x32_bf16(
                    a_cur[ni], b[fi], acc[fi][ni], 0, 0, 0);
        __builtin_amdgcn_s_setprio(0);

        if (rs == 8 && cblk < 3) {
            __syncthreads();              // all reads of Xs for this cblk done
            STAGE_WRITE();                // overwrite with next cblk
            __syncthreads();              // writes visible
        }
        #pragma unroll
        for (int ni = 0; ni < 4; ++ni) a_cur[ni] = a_nxt[ni];
    }

    // ---- epilogue: D col = pixel = lane&15, row = k = (lane>>4)*4 + reg (m89) ----
    const int pix0  = h0 * 56 + mw * 112 + (lane & 15);
    const int krow0 = n * 128 + nw * 64 + ((lane >> 4) * 4);
    #pragma unroll
    for (int fi = 0; fi < 7; ++fi)
        #pragma unroll
        for (int ni = 0; ni < 4; ++ni)
            #pragma unroll
            for (int j = 0; j < 4; ++j)
                out[(size_t)(krow0 + ni * 16 + j) * 3136 + pix0 + fi * 16] = acc[fi][ni][j];
#undef LOADA
#undef STAGE_LOAD
#undef STAGE_WRITE
}

extern "C" void kernel_launch(void* const* d_in, const int* in_sizes, int n_in,
                              void* d_out, int out_size, void* d_ws, size_t ws_size,
                              hipStream_t stream) {
    const float* x = (const float*)d_in[0];   // 25,690,112 f32
    const float* w = (const float*)d_in[1];   //    147,456 f32
    float* out = (float*)d_out;               // 25,690,112 f32

    // Workspace: xq (NHWC bf16, 51.4MB) + wq ([cblk][rs][k][c32] bf16, 0.3MB)
    unsigned short* xq = (unsigned short*)d_ws;
    unsigned short* wq = xq + (size_t)25690112;

    quant_kernel<<<3136 + 36, 256, 0, stream>>>(x, w, xq, wq);
    conv_kernel <<<896,       256, 0, stream>>>(xq, wq, out);
}

// Round 5
// 248.246 us; speedup vs baseline: 4.0722x; 4.0722x over previous
//
#include <hip/hip_runtime.h>
#include <hip/hip_bf16.h>

// BFConv2d on MI355X: BFP(8,16)-quantize x and w to bf16 (exact), then
// implicit-GEMM 3x3 conv with mfma_f32_16x16x32_bf16, fp32 accumulation.
// x (64,128,56,56) f32 NCHW; w (128,128,3,3) f32 OIHW; out (64,128,56,56) f32.
//
// r5: weights staged in LDS (8KB/step unique, vs 32KB/step L2 re-reads in r3
// whose 56B/cy L2 ceiling = the measured 28% MfmaUtil). Ws triple-buffered,
// filled by global_load_lds 2 steps ahead; raw s_barrier + COUNTED vmcnt
// (never 0 in loop) keeps prefetch in flight across barriers. cc-major LDS
// layout [cc][entry][16B]: 2-way bank conflicts only, zero pad, 69.1KB/block
// -> 2 blocks/CU. launch_bounds(256,2): 2 waves/SIMD is the hard cap anyway
// (acc = 112 AGPR; r4 showed (256,4) forces vgpr+agpr<=128 -> acc spills).

using short8 = __attribute__((ext_vector_type(8))) short;
using f32x4  = __attribute__((ext_vector_type(4))) float;
using int4v  = __attribute__((ext_vector_type(4))) int;

#define XS_PLANE_B 5568        // 348 entries * 16B per cc-plane
#define XS_BUF_B   22272       // 4 cc-planes
#define WS_SLICE_B 8192        // [4 cc][128 k][16B]
#define WS_BASE_B  44544       // 2 * XS_BUF_B

#define GLL(GSRC, LDST) __builtin_amdgcn_global_load_lds(                      \
    (const __attribute__((address_space(1))) void*)(GSRC),                     \
    (__attribute__((address_space(3))) void*)(LDST), 16, 0, 0)

#define WAITV(N) asm volatile("s_waitcnt vmcnt(" #N ")" ::: "memory")
#define LGKM0()  asm volatile("s_waitcnt lgkmcnt(0)" ::: "memory")
#define BAR()    asm volatile("s_barrier" ::: "memory")

__device__ __forceinline__ unsigned short f2bf(float f) {
    union { float f; unsigned u; } v; v.f = f;
    return (unsigned short)(v.u >> 16);     // quantized values exact in bf16
}

__device__ __forceinline__ void quant16(const float* v, float* o) {
    float m = 0.f;
    #pragma unroll
    for (int i = 0; i < 16; ++i) m = fmaxf(m, fabsf(v[i]));
    if (m > 0.f) {
        float e     = floorf(log2f(m));     // matches jnp.floor(jnp.log2(m))
        float scale = exp2f(e - 7.0f);
        float inv   = exp2f(7.0f - e);
        #pragma unroll
        for (int i = 0; i < 16; ++i) {
            float q = rintf(v[i] * inv);    // round half-to-even == jnp.round
            q = fminf(fmaxf(q, -127.f), 127.f);
            o[i] = q * scale;
        }
    } else {
        #pragma unroll
        for (int i = 0; i < 16; ++i) o[i] = 0.f;
    }
}

// Fused quantization. Blocks 0..3135: x NCHW f32 -> xq NHWC bf16 via LDS
// transpose. Blocks 3136..3171: w OIHW f32 -> wq [slice][cc][k][8] bf16
// (slice = cblk*9+rs, cc = (c&31)>>3) so a Ws slice is 8KB linear.
__global__ __launch_bounds__(256) void quant_kernel(const float* __restrict__ x,
                                                    const float* __restrict__ w,
                                                    unsigned short* __restrict__ xq,
                                                    unsigned short* __restrict__ wq) {
    __shared__ float T[128 * 68];
    const int bid = blockIdx.x;
    const int t   = threadIdx.x;

    if (bid < 3136) {
        const int n  = bid / 49;
        const int p0 = (bid % 49) * 64;
        const float* src = x + (size_t)n * 128 * 3136 + p0;
        #pragma unroll
        for (int i = 0; i < 8; ++i) {
            const int c  = (t >> 4) + i * 16;
            const int ch = t & 15;
            *reinterpret_cast<float4*>(&T[c * 68 + ch * 4]) =
                *reinterpret_cast<const float4*>(src + (size_t)c * 3136 + ch * 4);
        }
        __syncthreads();
        const int c = t & 127;
        #pragma unroll
        for (int i = 0; i < 2; ++i) {
            const int grp = (t >> 7) + 2 * i;
            float v[16];
            #pragma unroll
            for (int j2 = 0; j2 < 4; ++j2) {
                float4 f = *reinterpret_cast<const float4*>(&T[c * 68 + grp * 16 + j2 * 4]);
                v[j2*4+0] = f.x; v[j2*4+1] = f.y; v[j2*4+2] = f.z; v[j2*4+3] = f.w;
            }
            float o[16];
            quant16(v, o);
            unsigned short* dst = xq + ((size_t)(n * 3136 + p0 + grp * 16)) * 128 + c;
            #pragma unroll
            for (int j = 0; j < 16; ++j) dst[(size_t)j * 128] = f2bf(o[j]);
        }
    } else {
        const int G    = (bid - 3136) * 256 + t;   // 0..9215
        const int k    = G / 72;
        const int base = (G % 72) * 16;            // flat idx2 = c*9 + r*3 + s
        const float* src = w + (size_t)k * 1152 + base;
        float v[16];
        #pragma unroll
        for (int i = 0; i < 4; ++i) {
            float4 f = *reinterpret_cast<const float4*>(src + i * 4);
            v[i*4+0] = f.x; v[i*4+1] = f.y; v[i*4+2] = f.z; v[i*4+3] = f.w;
        }
        float o[16];
        quant16(v, o);
        #pragma unroll
        for (int j = 0; j < 16; ++j) {
            int idx2 = base + j;
            int c    = idx2 / 9;
            int rs   = idx2 % 9;
            int slice = (c >> 5) * 9 + rs;
            int c32  = c & 31;
            wq[(((size_t)slice * 4 + (c32 >> 3)) * 128 + k) * 8 + (c32 & 7)] = f2bf(o[j]);
        }
    }
}

// Implicit-GEMM conv. Per WG: n fixed, 4 output rows (224 px), all 128 k.
// Waves 2x2: wave tile = 112 px x 64 k = 7 M x 4 N frags (16x16x32 bf16).
// Both operands from LDS. Ws: triple-buffered 8KB slices via global_load_lds
// 2 steps ahead; Xs: double-buffered, reg-staged (sreg at rs0, write at rs2).
__global__ __launch_bounds__(256, 2) void conv_kernel(const unsigned short* __restrict__ xq,
                                                      const unsigned short* __restrict__ wq,
                                                      float* __restrict__ out) {
    __shared__ __align__(16) char LDSm[WS_BASE_B + 3 * WS_SLICE_B];  // 69,120B

    const int b0   = blockIdx.x;                   // 896 = 64 n * 14 h-tiles
    const int bid  = (b0 & 7) * 112 + (b0 >> 3);   // XCD swizzle (896%8==0)
    const int n    = bid / 14;
    const int h0   = (bid % 14) * 4;
    const int t    = threadIdx.x;
    const int lane = t & 63;
    const int wave = t >> 6;
    const int mw   = wave >> 1;                    // pixel half
    const int nw   = wave & 1;                     // k half

    char* XsB = LDSm;
    char* WsB = LDSm + WS_BASE_B;

    // ---- Xs staging descriptors: 6 chunks/thread (1392 = 348 ent x 4 cc) ----
    const unsigned short* sbase[6];
    int  soff[6];
    bool svalid[6], sact[6];
    #pragma unroll
    for (int it = 0; it < 6; ++it) {
        int i   = t + it * 256;
        bool act = i < 1392;
        int e   = i >> 2, cc = i & 3;
        int row = e / 58, pw = e % 58;
        int h   = h0 - 1 + row, w_ = pw - 1;
        bool inb = act && (unsigned)h < 56u && (unsigned)w_ < 56u;
        int gidx = inb ? (n * 3136 + h * 56 + w_) : 0;
        sbase[it]  = xq + (size_t)gidx * 128 + cc * 8;   // +cblk*32 later
        soff[it]   = cc * XS_PLANE_B + e * 16;           // bytes, cc-major
        svalid[it] = inb;
        sact[it]   = act;
    }
    int4v sreg[6];

#define STAGE_LOAD(CB) do {                                                    \
    _Pragma("unroll")                                                          \
    for (int it = 0; it < 6; ++it)                                             \
        sreg[it] = svalid[it]                                                  \
            ? *reinterpret_cast<const int4v*>(sbase[it] + (size_t)(CB) * 32)   \
            : int4v{0, 0, 0, 0};                                               \
} while (0)

#define STAGE_WRITE(BUFB) do {                                                 \
    _Pragma("unroll")                                                          \
    for (int it = 0; it < 6; ++it)                                             \
        if (sact[it])                                                          \
            *reinterpret_cast<int4v*>(XsB + (BUFB) + soff[it]) = sreg[it];     \
} while (0)

    // ---- Ws prefetch: 2 global_load_lds per wave per step (8KB/slice) ----
#define WS_GLL(SLICE) do {                                                     \
    const unsigned short* gsrc = wq + (size_t)(SLICE) * 4096;                  \
    char* ldst = WsB + ((SLICE) % 3) * WS_SLICE_B;                             \
    GLL(gsrc + (size_t)(wave * 128 + lane) * 8,      ldst + wave * 2048);      \
    GLL(gsrc + (size_t)(wave * 128 + 64 + lane) * 8, ldst + wave * 2048 + 1024);\
} while (0)

    // ---- fragment byte offsets (cc-major, conflict-free 2-way) ----
    int boff[7];
    #pragma unroll
    for (int fi = 0; fi < 7; ++fi) {
        int m  = mw * 112 + fi * 16 + (lane & 15);
        int dh = m / 56, w_ = m % 56;
        boff[fi] = (lane >> 4) * XS_PLANE_B + (dh * 58 + w_) * 16;
    }
    int aoff[4];
    #pragma unroll
    for (int ni = 0; ni < 4; ++ni)
        aoff[ni] = (lane >> 4) * 2048 + (nw * 64 + ni * 16 + (lane & 15)) * 16;

    f32x4 acc[7][4];
    #pragma unroll
    for (int fi = 0; fi < 7; ++fi)
        #pragma unroll
        for (int ni = 0; ni < 4; ++ni)
            acc[fi][ni] = f32x4{0.f, 0.f, 0.f, 0.f};

    // ---- prologue: slices 0,1 in flight; Xs cblk0 staged ----
    WS_GLL(0);
    WS_GLL(1);
    STAGE_LOAD(0);
    WAITV(0);
    STAGE_WRITE(0);
    LGKM0();
    BAR();

    #pragma unroll
    for (int s = 0; s < 36; ++s) {
        const int cblk = s / 9;
        const int rs   = s % 9;
        const char* WsS = WsB + (s % 3) * WS_SLICE_B;
        const char* XsS = XsB + (cblk & 1) * XS_BUF_B;
        const int rsB   = ((rs / 3) * 58 + (rs % 3)) * 16;

        if (s + 2 < 36) WS_GLL(s + 2);               // 2-step weight prefetch
        if (rs == 0 && cblk < 3) STAGE_LOAD(cblk + 1);

        short8 a[4], b[7];
        #pragma unroll
        for (int ni = 0; ni < 4; ++ni)
            a[ni] = *reinterpret_cast<const short8*>(WsS + aoff[ni]);
        #pragma unroll
        for (int fi = 0; fi < 7; ++fi)
            b[fi] = *reinterpret_cast<const short8*>(XsS + boff[fi] + rsB);

        if (rs == 2 && cblk < 3) {
            WAITV(4);                                // drain sregs (oldest 6)
            STAGE_WRITE(((cblk + 1) & 1) * XS_BUF_B);
        }

        __builtin_amdgcn_s_setprio(1);
        #pragma unroll
        for (int fi = 0; fi < 7; ++fi)
            #pragma unroll
            for (int ni = 0; ni < 4; ++ni)
                acc[fi][ni] = __builtin_amdgcn_mfma_f32_16x16x32_bf16(
                    a[ni], b[fi], acc[fi][ni], 0, 0, 0);
        __builtin_amdgcn_s_setprio(0);

        // end-of-step: slice s+1 must be resident; keep newer loads in flight
        if (s < 35) {
            if ((rs == 0 || rs == 1) && cblk < 3) WAITV(8);  // keep sreg6+gll2
            else if (s == 34)                     WAITV(0);
            else                                  WAITV(2);  // keep gll(s+2)
            LGKM0();
            BAR();
        }
    }

    // ---- epilogue: D col = pixel = lane&15, row = k = (lane>>4)*4 + reg ----
    const int pix0  = h0 * 56 + mw * 112 + (lane & 15);
    const int krow0 = n * 128 + nw * 64 + ((lane >> 4) * 4);
    #pragma unroll
    for (int fi = 0; fi < 7; ++fi)
        #pragma unroll
        for (int ni = 0; ni < 4; ++ni)
            #pragma unroll
            for (int j = 0; j < 4; ++j)
                out[(size_t)(krow0 + ni * 16 + j) * 3136 + pix0 + fi * 16] = acc[fi][ni][j];
#undef WS_GLL
#undef STAGE_LOAD
#undef STAGE_WRITE
}

extern "C" void kernel_launch(void* const* d_in, const int* in_sizes, int n_in,
                              void* d_out, int out_size, void* d_ws, size_t ws_size,
                              hipStream_t stream) {
    const float* x = (const float*)d_in[0];   // 25,690,112 f32
    const float* w = (const float*)d_in[1];   //    147,456 f32
    float* out = (float*)d_out;               // 25,690,112 f32

    // Workspace: xq (NHWC bf16, 51.4MB) + wq ([slice][cc][k][8] bf16, 0.3MB)
    unsigned short* xq = (unsigned short*)d_ws;
    unsigned short* wq = xq + (size_t)25690112;

    quant_kernel<<<3136 + 36, 256, 0, stream>>>(x, w, xq, wq);
    conv_kernel <<<896,       256, 0, stream>>>(xq, wq, out);
}